// Round 2
// baseline (267.660 us; speedup 1.0000x reference)
//
#include <hip/hip_runtime.h>

// SimpleRNN fused kernel for MI355X (gfx950).  B=32768, T=28, I=28, H=128, C=10.
//
// Transposed recurrence D[h][b] = W * S^T:
//   A-operand = W (m=h_out) resident in VGPRs; B-operand = S^T from LDS
//   (k=h_in contiguous per lane -> b64 reads); D rows (4 consecutive h) pack
//   to b64 writes of row-major S[b][h] -> no transpose between steps.
// MFMA 16x16x32 bf16 layouts (m89/m91/m120):
//   A: A[m=lane&15][k=(lane>>4)*8+j]   B: B[k=(lane>>4)*8+j][n=lane&15]
//   D: D[(lane>>4)*4+reg][lane&15]
//
// R2: 32 batch rows/block, grid 1024 -> 4 blocks/CU = 16 waves/CU
// (R1 was 2 blocks/CU, 19.8% occupancy, latency-bound at 102 us).
// Wave w: h-half (w>>1)*64 (4 m-tiles), batch-half (w&1)*16 (1 n-tile).
// VALU diet: bias as MFMA C-init, v_cvt_pk_bf16_f32 packing, exp2+rcp tanh.
// LDS: double-buffered S[32][132] bf16 = 16896 B/block (stride 132: b64
// read/write conflict-free, measured 0 conflicts in R1).

#define T_STEPS 28
#define I_DIM   28
#define S_STRIDE 132

typedef __attribute__((ext_vector_type(4))) float f32x4;
typedef __attribute__((ext_vector_type(8))) short short8;

#define MFMA16 __builtin_amdgcn_mfma_f32_16x16x32_bf16

__device__ __forceinline__ unsigned pack2(float lo, float hi) {
#if __has_builtin(__builtin_amdgcn_cvt_pk_bf16_f32)
  auto p = __builtin_amdgcn_cvt_pk_bf16_f32(lo, hi);   // D.l=bf16(src0), D.h=bf16(src1), RNE
  return __builtin_bit_cast(unsigned, p);
#else
  unsigned a = __builtin_bit_cast(unsigned, lo);
  a += 0x7FFFu + ((a >> 16) & 1u);
  unsigned b = __builtin_bit_cast(unsigned, hi);
  b += 0x7FFFu + ((b >> 16) & 1u);
  return (a >> 16) | (b & 0xFFFF0000u);
#endif
}

__device__ __forceinline__ float bf2f(unsigned short s) {
  return __builtin_bit_cast(float, (unsigned)s << 16);
}

__device__ __forceinline__ short8 to_frag(f32x4 a, f32x4 b) {
  union { unsigned u[4]; short8 v; } r;
  r.u[0] = pack2(a[0], a[1]);
  r.u[1] = pack2(a[2], a[3]);
  r.u[2] = pack2(b[0], b[1]);
  r.u[3] = pack2(b[2], b[3]);
  return r.v;
}

__device__ __forceinline__ short8 load_sfrag(const unsigned short* sp, int off) {
  union { uint2 d[2]; short8 v; } r;
  r.d[0] = *(const uint2*)(sp + off);
  r.d[1] = *(const uint2*)(sp + off + 4);
  return r.v;
}

__device__ __forceinline__ f32x4 tanh4(f32x4 z) {
  // tanh(z) = 1 - 2/(exp2(z*2log2e)+1); vector mul/add/fma can pair as v_pk_*_f32
  const float k = 2.8853900817779268f;  // 2*log2(e)
  f32x4 t = z * k;
  f32x4 e;
#pragma unroll
  for (int i = 0; i < 4; ++i) e[i] = __builtin_amdgcn_exp2f(t[i]);
  f32x4 d = e + 1.0f;
  f32x4 r;
#pragma unroll
  for (int i = 0; i < 4; ++i) r[i] = __builtin_amdgcn_rcpf(d[i]);
  return 1.0f - 2.0f * r;
}

__global__ __launch_bounds__(256, 4) void rnn_fused(
    const float* __restrict__ x,  const float* __restrict__ Uw,
    const float* __restrict__ Ub, const float* __restrict__ Ww,
    const float* __restrict__ Wb, const float* __restrict__ Vw,
    const float* __restrict__ Vb, float* __restrict__ out) {
  __shared__ __align__(16) unsigned short Sbuf[2][32 * S_STRIDE];

  const int tid  = threadIdx.x;
  const int w    = tid >> 6;
  const int lane = tid & 63;
  const int l15  = lane & 15;
  const int q    = lane >> 4;           // 0..3
  const int mrow = (w >> 1) * 64;       // h base for this wave
  const int ncol = (w & 1) * 16;        // batch base within block
  const int b0   = blockIdx.x * 32;

  const f32x4 zero4 = {0.f, 0.f, 0.f, 0.f};

  // ---- persistent register fragments: W (A-op), U (A-op), bias-as-C ----
  short8 wfrag[4][4];   // [mt][kt]
  short8 ufrag[4];      // [mt], K=32 padded (k>=28 zeroed in A => B garbage annihilated)
  f32x4  bias[4];       // Ub[h]+Wb[h] at D rows h = mrow + mt*16 + q*4 + r
#pragma unroll
  for (int mt = 0; mt < 4; ++mt) {
    const int h = mrow + mt * 16 + l15;
    const float* wp = Ww + h * 128 + q * 8;
#pragma unroll
    for (int kt = 0; kt < 4; ++kt) {
      wfrag[mt][kt] = to_frag(*(const f32x4*)wp, *(const f32x4*)(wp + 4));
      wp += 32;
    }
    const float* up = Uw + h * I_DIM + q * 8;
    f32x4 u0 = *(const f32x4*)up;
    f32x4 u1 = zero4;
    if (q < 3) u1 = *(const f32x4*)(up + 4);
    ufrag[mt] = to_frag(u0, u1);
    const int hb = mrow + mt * 16 + q * 4;
    bias[mt] = *(const f32x4*)(Wb + hb) + *(const f32x4*)(Ub + hb);
  }

  // x B-operand frag: n = batch = lane&15, k = i = q*8+j.
  // hi half for q==3 reads a VALID in-row address (row start); its products
  // are multiplied by ufrag's zeroed k>=28 entries -> contributes 0, no OOB.
  const float* xlo = x + (size_t)(b0 + ncol + l15) * (T_STEPS * I_DIM) + q * 8;
  const float* xhi = x + (size_t)(b0 + ncol + l15) * (T_STEPS * I_DIM)
                       + ((q < 3) ? q * 8 + 4 : 0);

  const int ro = (ncol + l15) * S_STRIDE;   // LDS element offset (row base)
  f32x4 acc[4];

  // ---- t = 0 (S=0: projection only) ----
  {
    f32x4 xa = *(const f32x4*)xlo;
    f32x4 xb = *(const f32x4*)xhi;
    xlo += I_DIM; xhi += I_DIM;
    short8 xf = to_frag(xa, xb);
    unsigned short* wp = &Sbuf[1][0];
#pragma unroll
    for (int mt = 0; mt < 4; ++mt) {
      acc[mt] = MFMA16(ufrag[mt], xf, bias[mt], 0, 0, 0);
      f32x4 th = tanh4(acc[mt]);
      uint2 dd; dd.x = pack2(th[0], th[1]); dd.y = pack2(th[2], th[3]);
      *(uint2*)(wp + ro + mrow + mt * 16 + q * 4) = dd;
    }
  }
  __syncthreads();

  // ---- t = 1 .. 27 ----
#pragma unroll 1
  for (int t = 1; t < T_STEPS; ++t) {
    // issue x loads early; covered by the recurrence MFMAs
    f32x4 xa = *(const f32x4*)xlo;
    f32x4 xb = *(const f32x4*)xhi;
    xlo += I_DIM; xhi += I_DIM;

    const unsigned short* sp = &Sbuf[t & 1][0];
#pragma unroll
    for (int mt = 0; mt < 4; ++mt) acc[mt] = bias[mt];

#pragma unroll
    for (int kt = 0; kt < 4; ++kt) {
      short8 s0 = load_sfrag(sp, ro + kt * 32 + q * 8);
#pragma unroll
      for (int mt = 0; mt < 4; ++mt)
        acc[mt] = MFMA16(wfrag[mt][kt], s0, acc[mt], 0, 0, 0);
    }

    short8 xf = to_frag(xa, xb);
#pragma unroll
    for (int mt = 0; mt < 4; ++mt)
      acc[mt] = MFMA16(ufrag[mt], xf, acc[mt], 0, 0, 0);

    unsigned short* wp = &Sbuf[(t + 1) & 1][0];
#pragma unroll
    for (int mt = 0; mt < 4; ++mt) {
      f32x4 th = tanh4(acc[mt]);
      uint2 dd; dd.x = pack2(th[0], th[1]); dd.y = pack2(th[2], th[3]);
      *(uint2*)(wp + ro + mrow + mt * 16 + q * 4) = dd;
    }
    __syncthreads();
  }

  // ---- epilogue: out[b][c] = sum_h S[b][h]*Vw[c][h] + Vb[c] ----
  // Final S is in Sbuf[(27+1)&1] = Sbuf[0]. 32 rows x 10 cols per block.
  {
    const unsigned short* sf = &Sbuf[0][0];
    const int r  = tid >> 3;        // 0..31
    const int c0 = tid & 7;         // col c0; threads with c0<2 also do c0+8
    const float* v0 = Vw + c0 * 128;
    const float* v1 = Vw + ((c0 & 1) + 8) * 128;
    const unsigned short* srow = sf + r * S_STRIDE;
    float a0 = 0.f, a1 = 0.f;
#pragma unroll 8
    for (int h = 0; h < 128; ++h) {
      float s = bf2f(srow[h]);
      a0 += s * v0[h];
      a1 += s * v1[h];
    }
    float* op = out + (size_t)(b0 + r) * 10;
    op[c0] = a0 + Vb[c0];
    if (c0 < 2) op[c0 + 8] = a1 + Vb[(c0 & 1) + 8];
  }
}

extern "C" void kernel_launch(void* const* d_in, const int* in_sizes, int n_in,
                              void* d_out, int out_size, void* d_ws, size_t ws_size,
                              hipStream_t stream) {
  const float* x  = (const float*)d_in[0];
  const float* Uw = (const float*)d_in[1];
  const float* Ub = (const float*)d_in[2];
  const float* Ww = (const float*)d_in[3];
  const float* Wb = (const float*)d_in[4];
  const float* Vw = (const float*)d_in[5];
  const float* Vb = (const float*)d_in[6];
  rnn_fused<<<1024, 256, 0, stream>>>(x, Uw, Ub, Ww, Wb, Vw, Vb, (float*)d_out);
}

// Round 3
// 216.141 us; speedup vs baseline: 1.2384x; 1.2384x over previous
//
#include <hip/hip_runtime.h>

// SimpleRNN fused kernel for MI355X (gfx950).  B=32768, T=28, I=28, H=128, C=10.
//
// Transposed recurrence D[h][b] = W * S^T:
//   A-operand = W (m=h_out) resident in VGPRs; B-operand = S^T from LDS
//   (k=h_in contiguous per lane -> b64 reads); D rows (4 consecutive h) pack
//   to b64 writes of row-major S[b][h] -> no transpose between steps.
// MFMA 16x16x32 bf16 layouts (m89/m91/m120):
//   A: A[m=lane&15][k=(lane>>4)*8+j]   B: B[k=(lane>>4)*8+j][n=lane&15]
//   D: D[(lane>>4)*4+reg][lane&15]
//
// R3: 32 batch rows/block, grid 1024 = 4 blocks/CU (16 waves/CU), with a
// 2m x 2n wave split so persistent regs fit the 128-VGPR cap WITHOUT spills
// (R2's 4m x 1n split needed ~140 regs under launch_bounds(256,4) -> 129 MB
// of scratch spill writes in-loop, 156 us).
//   wave w: mrow = w*32 (2 m-tiles); n-tiles 0,1 (batch cols 0-15,16-31).
//   persistent: wfrag[2][4]=32 + ufrag[2]=8 + bias[2]=8 = 48 VGPR; acc 16 (AGPR).
// LDS: double-buffered S[32][132] bf16 = 16896 B/block (stride 132: b64
// read/write conflict-free, measured 0 conflicts R1/R2).

#define T_STEPS 28
#define I_DIM   28
#define S_STRIDE 132

typedef __attribute__((ext_vector_type(4))) float f32x4;
typedef __attribute__((ext_vector_type(8))) short short8;

#define MFMA16 __builtin_amdgcn_mfma_f32_16x16x32_bf16

__device__ __forceinline__ unsigned pack2(float lo, float hi) {
#if __has_builtin(__builtin_amdgcn_cvt_pk_bf16_f32)
  auto p = __builtin_amdgcn_cvt_pk_bf16_f32(lo, hi);   // RNE pack
  return __builtin_bit_cast(unsigned, p);
#else
  unsigned a = __builtin_bit_cast(unsigned, lo);
  a += 0x7FFFu + ((a >> 16) & 1u);
  unsigned b = __builtin_bit_cast(unsigned, hi);
  b += 0x7FFFu + ((b >> 16) & 1u);
  return (a >> 16) | (b & 0xFFFF0000u);
#endif
}

__device__ __forceinline__ float bf2f(unsigned short s) {
  return __builtin_bit_cast(float, (unsigned)s << 16);
}

__device__ __forceinline__ short8 to_frag(f32x4 a, f32x4 b) {
  union { unsigned u[4]; short8 v; } r;
  r.u[0] = pack2(a[0], a[1]);
  r.u[1] = pack2(a[2], a[3]);
  r.u[2] = pack2(b[0], b[1]);
  r.u[3] = pack2(b[2], b[3]);
  return r.v;
}

__device__ __forceinline__ short8 load_sfrag(const unsigned short* sp, int off) {
  union { uint2 d[2]; short8 v; } r;
  r.d[0] = *(const uint2*)(sp + off);
  r.d[1] = *(const uint2*)(sp + off + 4);
  return r.v;
}

__device__ __forceinline__ f32x4 tanh4(f32x4 z) {
  // tanh(z) = 1 - 2/(exp2(z*2log2e)+1)
  const float k = 2.8853900817779268f;  // 2*log2(e)
  f32x4 t = z * k;
  f32x4 e;
#pragma unroll
  for (int i = 0; i < 4; ++i) e[i] = __builtin_amdgcn_exp2f(t[i]);
  f32x4 d = e + 1.0f;
  f32x4 r;
#pragma unroll
  for (int i = 0; i < 4; ++i) r[i] = __builtin_amdgcn_rcpf(d[i]);
  return 1.0f - 2.0f * r;
}

__global__ __launch_bounds__(256, 4) void rnn_fused(
    const float* __restrict__ x,  const float* __restrict__ Uw,
    const float* __restrict__ Ub, const float* __restrict__ Ww,
    const float* __restrict__ Wb, const float* __restrict__ Vw,
    const float* __restrict__ Vb, float* __restrict__ out) {
  __shared__ __align__(16) unsigned short Sbuf[2][32 * S_STRIDE];

  const int tid  = threadIdx.x;
  const int w    = tid >> 6;
  const int lane = tid & 63;
  const int l15  = lane & 15;
  const int q    = lane >> 4;           // 0..3
  const int mrow = w * 32;              // h base for this wave (2 m-tiles)
  const int b0   = blockIdx.x * 32;

  const f32x4 zero4 = {0.f, 0.f, 0.f, 0.f};

  // ---- persistent register fragments ----
  short8 wfrag[2][4];   // [mt][kt]  32 VGPR
  short8 ufrag[2];      // [mt], K=32 padded (k>=28 zeroed => B garbage annihilated)
  f32x4  bias[2];       // Ub[h]+Wb[h] at D rows h = mrow + mt*16 + q*4 + r
#pragma unroll
  for (int mt = 0; mt < 2; ++mt) {
    const int h = mrow + mt * 16 + l15;
    const float* wp = Ww + h * 128 + q * 8;
#pragma unroll
    for (int kt = 0; kt < 4; ++kt) {
      wfrag[mt][kt] = to_frag(*(const f32x4*)wp, *(const f32x4*)(wp + 4));
      wp += 32;
    }
    const float* up = Uw + h * I_DIM + q * 8;
    f32x4 u0 = *(const f32x4*)up;
    f32x4 u1 = zero4;
    if (q < 3) u1 = *(const f32x4*)(up + 4);
    ufrag[mt] = to_frag(u0, u1);
    const int hb = mrow + mt * 16 + q * 4;
    bias[mt] = *(const f32x4*)(Wb + hb) + *(const f32x4*)(Ub + hb);
  }

  // x B-operand frags: n = batch = nt*16 + lane&15, k = i = q*8+j.
  // q==3 hi-half reads a valid in-row address; annihilated by zeroed U cols.
  const float* xlo[2];
  const float* xhi[2];
#pragma unroll
  for (int nt = 0; nt < 2; ++nt) {
    const float* base = x + (size_t)(b0 + nt * 16 + l15) * (T_STEPS * I_DIM);
    xlo[nt] = base + q * 8;
    xhi[nt] = base + ((q < 3) ? q * 8 + 4 : 0);
  }

  int ro[2];
#pragma unroll
  for (int nt = 0; nt < 2; ++nt) ro[nt] = (nt * 16 + l15) * S_STRIDE;

  f32x4 acc[2][2];   // [mt][nt]

  // ---- t = 0 (S=0: projection only) ----
  {
    short8 xf[2];
#pragma unroll
    for (int nt = 0; nt < 2; ++nt) {
      f32x4 xa = *(const f32x4*)xlo[nt];
      f32x4 xb = *(const f32x4*)xhi[nt];
      xlo[nt] += I_DIM; xhi[nt] += I_DIM;
      xf[nt] = to_frag(xa, xb);
    }
    unsigned short* wp = &Sbuf[1][0];
#pragma unroll
    for (int mt = 0; mt < 2; ++mt)
#pragma unroll
      for (int nt = 0; nt < 2; ++nt) {
        f32x4 d = MFMA16(ufrag[mt], xf[nt], bias[mt], 0, 0, 0);
        f32x4 th = tanh4(d);
        uint2 dd; dd.x = pack2(th[0], th[1]); dd.y = pack2(th[2], th[3]);
        *(uint2*)(wp + ro[nt] + mrow + mt * 16 + q * 4) = dd;
      }
  }
  __syncthreads();

  // ---- t = 1 .. 27 ----
#pragma unroll 1
  for (int t = 1; t < T_STEPS; ++t) {
    // issue x loads early; latency covered by the recurrence MFMAs
    f32x4 xa[2], xb[2];
#pragma unroll
    for (int nt = 0; nt < 2; ++nt) {
      xa[nt] = *(const f32x4*)xlo[nt];
      xb[nt] = *(const f32x4*)xhi[nt];
      xlo[nt] += I_DIM; xhi[nt] += I_DIM;
    }

    const unsigned short* sp = &Sbuf[t & 1][0];
#pragma unroll
    for (int mt = 0; mt < 2; ++mt)
#pragma unroll
      for (int nt = 0; nt < 2; ++nt) acc[mt][nt] = bias[mt];

#pragma unroll
    for (int kt = 0; kt < 4; ++kt) {
      short8 s0 = load_sfrag(sp, ro[0] + kt * 32 + q * 8);
      short8 s1 = load_sfrag(sp, ro[1] + kt * 32 + q * 8);
#pragma unroll
      for (int mt = 0; mt < 2; ++mt) {
        acc[mt][0] = MFMA16(wfrag[mt][kt], s0, acc[mt][0], 0, 0, 0);
        acc[mt][1] = MFMA16(wfrag[mt][kt], s1, acc[mt][1], 0, 0, 0);
      }
    }

    short8 xf0 = to_frag(xa[0], xb[0]);
    short8 xf1 = to_frag(xa[1], xb[1]);
#pragma unroll
    for (int mt = 0; mt < 2; ++mt) {
      acc[mt][0] = MFMA16(ufrag[mt], xf0, acc[mt][0], 0, 0, 0);
      acc[mt][1] = MFMA16(ufrag[mt], xf1, acc[mt][1], 0, 0, 0);
    }

    unsigned short* wp = &Sbuf[(t + 1) & 1][0];
#pragma unroll
    for (int mt = 0; mt < 2; ++mt)
#pragma unroll
      for (int nt = 0; nt < 2; ++nt) {
        f32x4 th = tanh4(acc[mt][nt]);
        uint2 dd; dd.x = pack2(th[0], th[1]); dd.y = pack2(th[2], th[3]);
        *(uint2*)(wp + ro[nt] + mrow + mt * 16 + q * 4) = dd;
      }
    __syncthreads();
  }

  // ---- epilogue: out[b][c] = sum_h S[b][h]*Vw[c][h] + Vb[c] ----
  // Final S is in Sbuf[(27+1)&1] = Sbuf[0]. 32 rows x 10 cols per block.
  {
    const unsigned short* sf = &Sbuf[0][0];
    const int r  = tid >> 3;        // 0..31
    const int c0 = tid & 7;         // col c0; threads with c0<2 also do c0+8
    const float* v0 = Vw + c0 * 128;
    const float* v1 = Vw + ((c0 & 1) + 8) * 128;
    const unsigned short* srow = sf + r * S_STRIDE;
    float a0 = 0.f, a1 = 0.f;
#pragma unroll 8
    for (int h = 0; h < 128; ++h) {
      float s = bf2f(srow[h]);
      a0 += s * v0[h];
      a1 += s * v1[h];
    }
    float* op = out + (size_t)(b0 + r) * 10;
    op[c0] = a0 + Vb[c0];
    if (c0 < 2) op[c0 + 8] = a1 + Vb[(c0 & 1) + 8];
  }
}

extern "C" void kernel_launch(void* const* d_in, const int* in_sizes, int n_in,
                              void* d_out, int out_size, void* d_ws, size_t ws_size,
                              hipStream_t stream) {
  const float* x  = (const float*)d_in[0];
  const float* Uw = (const float*)d_in[1];
  const float* Ub = (const float*)d_in[2];
  const float* Ww = (const float*)d_in[3];
  const float* Wb = (const float*)d_in[4];
  const float* Vw = (const float*)d_in[5];
  const float* Vb = (const float*)d_in[6];
  rnn_fused<<<1024, 256, 0, stream>>>(x, Uw, Ub, Ww, Wb, Vw, Vb, (float*)d_out);
}

// Round 4
// 204.940 us; speedup vs baseline: 1.3060x; 1.0547x over previous
//
#include <hip/hip_runtime.h>

// SimpleRNN fused kernel for MI355X (gfx950).  B=32768, T=28, I=28, H=128, C=10.
//
// Transposed recurrence D[h][b] = W * S^T:
//   A-operand = W (m=h_out) resident in VGPRs; B-operand = S^T from LDS
//   (k=h_in contiguous per lane -> b128 reads); D rows (4 consecutive h) pack
//   to b64 writes of row-major S[b][h] -> no transpose between steps.
// MFMA 16x16x32 bf16 layouts (m89/m91/m120):
//   A: A[m=lane&15][k=(lane>>4)*8+j]   B: B[k=(lane>>4)*8+j][n=lane&15]
//   D: D[(lane>>4)*4+reg][lane&15]
//
// R4 (R3 was 107us, VALUBusy 45%, MfmaUtil 13% -> stall-bound):
//  - x software pipeline: loads for t+1 issue at top of step t, bf16-convert
//    at END of step t (full-step latency cover; only xf=8 regs live across
//    the barrier).
//  - S_STRIDE 132->136 (16B-aligned rows) -> single ds_read_b128 per frag.
//  - bias rides as MFMA C-operand at kt=0 (kills per-step acc-init movs).
//  - tanh = Pade(5,4) + v_med3 clamp: no exp (quarter-rate), 1 rcp.
// Grid 1024 x 256thr = 4 blocks/CU (16 waves/CU), launch_bounds(256,4);
// persistent regs: wfrag[2][4]=32 + ufrag[2]=8 + bias[2]=8 (no spills in R3).

#define T_STEPS 28
#define I_DIM   28
#define S_STRIDE 136

typedef __attribute__((ext_vector_type(4))) float f32x4;
typedef __attribute__((ext_vector_type(8))) short short8;
typedef __attribute__((ext_vector_type(4))) unsigned int uint4v;

#define MFMA16 __builtin_amdgcn_mfma_f32_16x16x32_bf16

__device__ __forceinline__ unsigned pack2(float lo, float hi) {
#if __has_builtin(__builtin_amdgcn_cvt_pk_bf16_f32)
  auto p = __builtin_amdgcn_cvt_pk_bf16_f32(lo, hi);   // RNE pack
  return __builtin_bit_cast(unsigned, p);
#else
  unsigned a = __builtin_bit_cast(unsigned, lo);
  a += 0x7FFFu + ((a >> 16) & 1u);
  unsigned b = __builtin_bit_cast(unsigned, hi);
  b += 0x7FFFu + ((b >> 16) & 1u);
  return (a >> 16) | (b & 0xFFFF0000u);
#endif
}

__device__ __forceinline__ float bf2f(unsigned short s) {
  return __builtin_bit_cast(float, (unsigned)s << 16);
}

__device__ __forceinline__ short8 to_frag(f32x4 a, f32x4 b) {
  union { unsigned u[4]; short8 v; } r;
  r.u[0] = pack2(a[0], a[1]);
  r.u[1] = pack2(a[2], a[3]);
  r.u[2] = pack2(b[0], b[1]);
  r.u[3] = pack2(b[2], b[3]);
  return r.v;
}

__device__ __forceinline__ short8 load_sfrag(const unsigned short* sp, int off) {
  uint4v d = *(const uint4v*)(sp + off);     // ds_read_b128, 16B aligned
  return __builtin_bit_cast(short8, d);
}

__device__ __forceinline__ f32x4 tanh4(f32x4 z) {
  // Pade(5,4): z*(945 + 105 z^2 + z^4) / (945 + 420 z^2 + 15 z^4), clamped.
  // Max abs err ~1.2e-3 (worst near |z|=3.5); den >= 945 -> no NaN/Inf.
  f32x4 x2 = z * z;
  f32x4 p = 945.0f + x2 * (105.0f + x2);
  f32x4 q = 945.0f + x2 * (420.0f + 15.0f * x2);
  f32x4 num = z * p;
  f32x4 r;
#pragma unroll
  for (int i = 0; i < 4; ++i) r[i] = __builtin_amdgcn_rcpf(q[i]);
  f32x4 t = num * r;
#pragma unroll
  for (int i = 0; i < 4; ++i) t[i] = __builtin_amdgcn_fmed3f(t[i], -1.0f, 1.0f);
  return t;
}

__global__ __launch_bounds__(256, 4) void rnn_fused(
    const float* __restrict__ x,  const float* __restrict__ Uw,
    const float* __restrict__ Ub, const float* __restrict__ Ww,
    const float* __restrict__ Wb, const float* __restrict__ Vw,
    const float* __restrict__ Vb, float* __restrict__ out) {
  __shared__ __align__(16) unsigned short Sbuf[2][32 * S_STRIDE];

  const int tid  = threadIdx.x;
  const int w    = tid >> 6;
  const int lane = tid & 63;
  const int l15  = lane & 15;
  const int q    = lane >> 4;           // 0..3
  const int mrow = w * 32;              // h base for this wave (2 m-tiles)
  const int b0   = blockIdx.x * 32;

  const f32x4 zero4 = {0.f, 0.f, 0.f, 0.f};

  // ---- persistent register fragments ----
  short8 wfrag[2][4];   // [mt][kt]  32 VGPR
  short8 ufrag[2];      // [mt], K=32 padded (k>=28 zeroed => B garbage annihilated)
  f32x4  bias[2];       // Ub[h]+Wb[h] at D rows h = mrow + mt*16 + q*4 + r
#pragma unroll
  for (int mt = 0; mt < 2; ++mt) {
    const int h = mrow + mt * 16 + l15;
    const float* wp = Ww + h * 128 + q * 8;
#pragma unroll
    for (int kt = 0; kt < 4; ++kt) {
      wfrag[mt][kt] = to_frag(*(const f32x4*)wp, *(const f32x4*)(wp + 4));
      wp += 32;
    }
    const float* up = Uw + h * I_DIM + q * 8;
    f32x4 u0 = *(const f32x4*)up;
    f32x4 u1 = zero4;
    if (q < 3) u1 = *(const f32x4*)(up + 4);
    ufrag[mt] = to_frag(u0, u1);
    const int hb = mrow + mt * 16 + q * 4;
    bias[mt] = *(const f32x4*)(Wb + hb) + *(const f32x4*)(Ub + hb);
  }

  // x B-operand frags: n = batch = nt*16 + lane&15, k = i = q*8+j.
  // q==3 hi-half reads a valid in-row address; annihilated by zeroed U cols.
  const float* xlo[2];
  const float* xhi[2];
#pragma unroll
  for (int nt = 0; nt < 2; ++nt) {
    const float* base = x + (size_t)(b0 + nt * 16 + l15) * (T_STEPS * I_DIM);
    xlo[nt] = base + q * 8;
    xhi[nt] = base + ((q < 3) ? q * 8 + 4 : 0);
  }

  int ro[2];
#pragma unroll
  for (int nt = 0; nt < 2; ++nt) ro[nt] = (nt * 16 + l15) * S_STRIDE;

  f32x4 acc[2][2];   // [mt][nt]
  short8 xf0, xf1;   // x frags for the CURRENT step (pipelined)

  // ---- t = 0 (S=0: projection only) + prefetch x(1) ----
  {
    f32x4 xa0 = *(const f32x4*)xlo[0], xb0 = *(const f32x4*)xhi[0];
    f32x4 xa1 = *(const f32x4*)xlo[1], xb1 = *(const f32x4*)xhi[1];
    // issue x(1) loads early
    xlo[0] += I_DIM; xhi[0] += I_DIM; xlo[1] += I_DIM; xhi[1] += I_DIM;
    f32x4 pa0 = *(const f32x4*)xlo[0], pb0 = *(const f32x4*)xhi[0];
    f32x4 pa1 = *(const f32x4*)xlo[1], pb1 = *(const f32x4*)xhi[1];

    xf0 = to_frag(xa0, xb0); xf1 = to_frag(xa1, xb1);
    unsigned short* wp = &Sbuf[1][0];
#pragma unroll
    for (int mt = 0; mt < 2; ++mt) {
      f32x4 d0 = MFMA16(ufrag[mt], xf0, bias[mt], 0, 0, 0);
      f32x4 d1 = MFMA16(ufrag[mt], xf1, bias[mt], 0, 0, 0);
      f32x4 t0 = tanh4(d0), t1 = tanh4(d1);
      uint2 dd0; dd0.x = pack2(t0[0], t0[1]); dd0.y = pack2(t0[2], t0[3]);
      uint2 dd1; dd1.x = pack2(t1[0], t1[1]); dd1.y = pack2(t1[2], t1[3]);
      *(uint2*)(wp + ro[0] + mrow + mt * 16 + q * 4) = dd0;
      *(uint2*)(wp + ro[1] + mrow + mt * 16 + q * 4) = dd1;
    }
    // convert prefetched x(1) -> frags for step 1 (vmcnt wait lands here)
    xf0 = to_frag(pa0, pb0); xf1 = to_frag(pa1, pb1);
  }
  __syncthreads();

  // ---- t = 1 .. 27 ----
#pragma unroll 1
  for (int t = 1; t < T_STEPS; ++t) {
    // issue x(t+1) loads FIRST (consumed at end of this step)
    f32x4 pa0, pb0, pa1, pb1;
    const bool more = (t < T_STEPS - 1);
    if (more) {
      xlo[0] += I_DIM; xhi[0] += I_DIM; xlo[1] += I_DIM; xhi[1] += I_DIM;
      pa0 = *(const f32x4*)xlo[0]; pb0 = *(const f32x4*)xhi[0];
      pa1 = *(const f32x4*)xlo[1]; pb1 = *(const f32x4*)xhi[1];
    }

    const unsigned short* sp = &Sbuf[t & 1][0];

    // kt = 0: bias as C-operand (no acc init)
    short8 sA = load_sfrag(sp, ro[0] + q * 8);
    short8 sB = load_sfrag(sp, ro[1] + q * 8);
#pragma unroll
    for (int mt = 0; mt < 2; ++mt) {
      acc[mt][0] = MFMA16(wfrag[mt][0], sA, bias[mt], 0, 0, 0);
      acc[mt][1] = MFMA16(wfrag[mt][0], sB, bias[mt], 0, 0, 0);
    }
#pragma unroll
    for (int kt = 1; kt < 4; ++kt) {
      sA = load_sfrag(sp, ro[0] + kt * 32 + q * 8);
      sB = load_sfrag(sp, ro[1] + kt * 32 + q * 8);
#pragma unroll
      for (int mt = 0; mt < 2; ++mt) {
        acc[mt][0] = MFMA16(wfrag[mt][kt], sA, acc[mt][0], 0, 0, 0);
        acc[mt][1] = MFMA16(wfrag[mt][kt], sB, acc[mt][1], 0, 0, 0);
      }
    }
#pragma unroll
    for (int mt = 0; mt < 2; ++mt) {
      acc[mt][0] = MFMA16(ufrag[mt], xf0, acc[mt][0], 0, 0, 0);
      acc[mt][1] = MFMA16(ufrag[mt], xf1, acc[mt][1], 0, 0, 0);
    }

    unsigned short* wp = &Sbuf[(t + 1) & 1][0];
#pragma unroll
    for (int mt = 0; mt < 2; ++mt)
#pragma unroll
      for (int nt = 0; nt < 2; ++nt) {
        f32x4 th = tanh4(acc[mt][nt]);
        uint2 dd; dd.x = pack2(th[0], th[1]); dd.y = pack2(th[2], th[3]);
        *(uint2*)(wp + ro[nt] + mrow + mt * 16 + q * 4) = dd;
      }

    // convert prefetched x -> next step's frags (full-step load cover)
    if (more) { xf0 = to_frag(pa0, pb0); xf1 = to_frag(pa1, pb1); }
    __syncthreads();
  }

  // ---- epilogue: out[b][c] = sum_h S[b][h]*Vw[c][h] + Vb[c] ----
  // Final S is in Sbuf[(27+1)&1] = Sbuf[0]. 32 rows x 10 cols per block.
  {
    const unsigned short* sf = &Sbuf[0][0];
    const int r  = tid >> 3;        // 0..31
    const int c0 = tid & 7;         // col c0; threads with c0<2 also do c0+8
    const float* v0 = Vw + c0 * 128;
    const float* v1 = Vw + ((c0 & 1) + 8) * 128;
    const unsigned short* srow = sf + r * S_STRIDE;
    float a0 = 0.f, a1 = 0.f;
#pragma unroll 8
    for (int h = 0; h < 128; ++h) {
      float s = bf2f(srow[h]);
      a0 += s * v0[h];
      a1 += s * v1[h];
    }
    float* op = out + (size_t)(b0 + r) * 10;
    op[c0] = a0 + Vb[c0];
    if (c0 < 2) op[c0 + 8] = a1 + Vb[(c0 & 1) + 8];
  }
}

extern "C" void kernel_launch(void* const* d_in, const int* in_sizes, int n_in,
                              void* d_out, int out_size, void* d_ws, size_t ws_size,
                              hipStream_t stream) {
  const float* x  = (const float*)d_in[0];
  const float* Uw = (const float*)d_in[1];
  const float* Ub = (const float*)d_in[2];
  const float* Ww = (const float*)d_in[3];
  const float* Wb = (const float*)d_in[4];
  const float* Vw = (const float*)d_in[5];
  const float* Vb = (const float*)d_in[6];
  rnn_fused<<<1024, 256, 0, stream>>>(x, Uw, Ub, Ww, Wb, Vw, Vb, (float*)d_out);
}